// Round 22
// baseline (104.784 us; speedup 1.0000x reference)
//
#include <hip/hip_runtime.h>
#include <hip/hip_bf16.h>
#include <math.h>

#define NB 64
#define LD 512
#define LP 1024
#define DD 128
#define KK 64

using half8 = __attribute__((ext_vector_type(8))) _Float16;
using half4 = __attribute__((ext_vector_type(4))) _Float16;
using f32x4 = __attribute__((ext_vector_type(4))) float;

// fast tanh: 1 - 2*rcp(e^{2x}+1) via v_rcp_f32 (no IEEE div sequence).
__device__ __forceinline__ float ftanh(float x) {
    float e = __expf(2.0f * x);
    return 1.0f - 2.0f * __builtin_amdgcn_rcpf(e + 1.0f);
}

__global__ void k_sentinel(float* out) {
    if (threadIdx.x == 0 && blockIdx.x == 0) out[0] = 1000.0f;
}

// ---------------- merged front-end: drug conv + targ conv + WbT + Wx/Wp ----------------
__global__ void k_convprep(const float* __restrict__ drug, _Float16* __restrict__ drug_h,
                           const float* __restrict__ targ, _Float16* __restrict__ targ_h,
                           const float* __restrict__ Wb, _Float16* __restrict__ WbT,
                           const float* __restrict__ Wx, _Float16* __restrict__ Wx_h,
                           const float* __restrict__ Wp, _Float16* __restrict__ Wp_h)
{
    int bid = blockIdx.x, tid = threadIdx.x;
    if (bid < 2048) {
        const float* in = (bid < 1024) ? drug : targ;
        _Float16* out = (bid < 1024) ? drug_h : targ_h;
        int n = (bid < 1024) ? (NB * LD * DD) : (NB * LP * DD);
        int blk = bid & 1023;
        int i = (blk * 256 + tid) * 4;
        int stride = 1024 * 256 * 4;
        for (; i < n; i += stride) {
            float4 v = *reinterpret_cast<const float4*>(in + i);
            half4 h;
            h.x = (_Float16)v.x; h.y = (_Float16)v.y; h.z = (_Float16)v.z; h.w = (_Float16)v.w;
            *reinterpret_cast<half4*>(out + i) = h;
        }
    } else if (bid < 2112) {
        int t = (bid - 2048) * 256 + tid;
        int d = t >> 7, e = t & 127;
        WbT[t] = (_Float16)Wb[e * 128 + d];
    } else {
        int q = bid - 2112;
        const float* src = (q < 8) ? Wx : Wp;
        _Float16* dst = (q < 8) ? Wx_h : Wp_h;
        int i = ((q & 7) * 256 + tid) * 4;
        float4 v = *reinterpret_cast<const float4*>(src + i);
        half4 h;
        h.x = (_Float16)v.x; h.y = (_Float16)v.y; h.z = (_Float16)v.z; h.w = (_Float16)v.w;
        *reinterpret_cast<half4*>(dst + i) = h;
    }
}

// ---------------- merged NT GEMM dispatch: Wxd + Wpt + tb in one grid ----------------
__global__ __launch_bounds__(256)
void k_gemm3(const _Float16* __restrict__ drug_h, const _Float16* __restrict__ targ_h,
             const _Float16* __restrict__ WbT_h, const _Float16* __restrict__ Wx_h,
             const _Float16* __restrict__ Wp_h,
             _Float16* __restrict__ tb_h, _Float16* __restrict__ Wxd_h,
             _Float16* __restrict__ Wpt_h)
{
    __shared__ alignas(16) _Float16 smem[64 * 72 + 128 * 72];
    _Float16* As = smem;
    _Float16* Bs = smem + 64 * 72;

    int bid = blockIdx.x;
    const _Float16 *A, *Bm;
    _Float16* Out;
    long sA, sB, sOut;
    int N, tilesN, t;
    const int Kd = 128;
    if (bid < 256)      { A = Wx_h;  sA = 0;            Bm = drug_h; sB = (long)LD * DD; Out = Wxd_h; sOut = (long)KK * LD; N = LD;  tilesN = 4; t = bid; }
    else if (bid < 768) { A = Wp_h;  sA = 0;            Bm = targ_h; sB = (long)LP * DD; Out = Wpt_h; sOut = (long)KK * LP; N = LP;  tilesN = 8; t = bid - 256; }
    else                { A = targ_h; sA = (long)LP * DD; Bm = WbT_h; sB = 0;            Out = tb_h;  sOut = (long)LP * DD; N = 128; tilesN = 1; t = bid - 768; }

    int tpb = (tilesN == 1) ? 16 : tilesN;
    int b = t / tpb;
    int q = t % tpb;
    int m0 = (tilesN == 1) ? q * 64 : 0;
    int n0 = (tilesN == 1) ? 0 : q * 128;

    const _Float16* Ab = A + (long)b * sA;
    const _Float16* Bb = Bm + (long)b * sB;

    int tid = threadIdx.x;
    int lane = tid & 63;
    int wid = tid >> 6;
    int wm = wid & 1, wn = wid >> 1;

    f32x4 acc[2][4];
#pragma unroll
    for (int i = 0; i < 2; i++)
#pragma unroll
        for (int j = 0; j < 4; j++) acc[i][j] = (f32x4)(0.0f);

    for (int k0 = 0; k0 < Kd; k0 += 64) {
#pragma unroll
        for (int i = 0; i < 2; i++) {
            int c = tid + i * 256;
            int row = c >> 3, col = c & 7;
            int4 v = *reinterpret_cast<const int4*>(Ab + (long)(m0 + row) * Kd + k0 + col * 8);
            *reinterpret_cast<int4*>(&As[row * 72 + col * 8]) = v;
        }
#pragma unroll
        for (int i = 0; i < 4; i++) {
            int c = tid + i * 256;
            int row = c >> 3, col = c & 7;
            int4 v = *reinterpret_cast<const int4*>(Bb + (long)(n0 + row) * Kd + k0 + col * 8);
            *reinterpret_cast<int4*>(&Bs[row * 72 + col * 8]) = v;
        }
        __syncthreads();
#pragma unroll
        for (int kk = 0; kk < 64; kk += 32) {
            int klane = kk + 8 * (lane >> 4);
            half8 af[2], bfr[4];
#pragma unroll
            for (int fm = 0; fm < 2; fm++)
                af[fm] = *reinterpret_cast<const half8*>(&As[(wm * 32 + fm * 16 + (lane & 15)) * 72 + klane]);
#pragma unroll
            for (int fn = 0; fn < 4; fn++)
                bfr[fn] = *reinterpret_cast<const half8*>(&Bs[(wn * 64 + fn * 16 + (lane & 15)) * 72 + klane]);
#pragma unroll
            for (int fm = 0; fm < 2; fm++)
#pragma unroll
                for (int fn = 0; fn < 4; fn++)
                    acc[fm][fn] = __builtin_amdgcn_mfma_f32_16x16x32_f16(af[fm], bfr[fn], acc[fm][fn], 0, 0, 0);
        }
        __syncthreads();
    }

    long ob = (long)b * sOut;
#pragma unroll
    for (int fm = 0; fm < 2; fm++)
#pragma unroll
        for (int fn = 0; fn < 4; fn++)
#pragma unroll
            for (int r = 0; r < 4; r++) {
                int row = m0 + wm * 32 + fm * 16 + (lane >> 4) * 4 + r;
                int col = n0 + wn * 64 + fn * 16 + (lane & 15);
                Out[ob + (long)row * N + col] = (_Float16)acc[fm][fn][r];
            }
}

// ---------------- templated side body for the fused score kernel ----------------
// FMA = RES/32 (2 -> RES=64 for side C; 4 -> RES=128 for side P).
// Per step (2 barriers): (C) Ss(s) visible, Cts free -> [sreg prefetch s+1, aw load s]
//   -> GEMM1 -> tanh -> Cts -> (B) Cts visible, Ss free -> GEMM2 (aw regs) -> Ss(s+1) write.
template<int FMA>
__device__ __forceinline__ void score_side(
    const _Float16* __restrict__ R, const _Float16* __restrict__ S,
    const _Float16* __restrict__ W, const _Float16* __restrict__ Add,
    const float* __restrict__ wv, float* __restrict__ out,
    int n0, int nsteps, int Ntot, int sW,
    _Float16* Ss, _Float16* Cts, float* wsh, int tid)
{
    constexpr int RES = FMA * 32;
    constexpr int HRES = RES / 2;
    int lane = tid & 63;
    int wid = tid >> 6;
    int wm = wid & 1, wn = wid >> 1;

    // resident fragments in registers (MFMA B-operand)
    half8 af[FMA][4];
#pragma unroll
    for (int fm = 0; fm < FMA; fm++)
#pragma unroll
        for (int kk = 0; kk < 4; kk++) {
            int row = n0 + wm * HRES + fm * 16 + (lane & 15);
            int col = kk * 32 + 8 * (lane >> 4);
            af[fm][kk] = *reinterpret_cast<const half8*>(R + (long)row * DD + col);
        }
    if (tid < 64) wsh[tid] = wv[tid];

    // streamed-tile register pipeline (named scalars)
    int rS = tid >> 4, cS = (tid & 15) * 8;
    int4 s0_, s1_, s2_, s3_;
    s0_ = *reinterpret_cast<const int4*>(S + (long)(rS)      * DD + cS);
    s1_ = *reinterpret_cast<const int4*>(S + (long)(rS + 16) * DD + cS);
    s2_ = *reinterpret_cast<const int4*>(S + (long)(rS + 32) * DD + cS);
    s3_ = *reinterpret_cast<const int4*>(S + (long)(rS + 48) * DD + cS);
    *reinterpret_cast<int4*>(&Ss[(rS)      * 136 + cS]) = s0_;
    *reinterpret_cast<int4*>(&Ss[(rS + 16) * 136 + cS]) = s1_;
    *reinterpret_cast<int4*>(&Ss[(rS + 32) * 136 + cS]) = s2_;
    *reinterpret_cast<int4*>(&Ss[(rS + 48) * 136 + cS]) = s3_;

    half8 aw00_, aw01_, aw10_, aw11_;
    long wbase0 = (long)(wm * 32 + (lane & 15)) * sW + 8 * (lane >> 4);

    f32x4 acc2[2][FMA];
#pragma unroll
    for (int i = 0; i < 2; i++)
#pragma unroll
        for (int j = 0; j < FMA; j++) acc2[i][j] = (f32x4)(0.0f);

    for (int s = 0; s < nsteps; s++) {
        __syncthreads();                  // (C) Ss(s) visible; Cts free
        if (s + 1 < nsteps) {
            int sn = (s + 1) * 64;
            s0_ = *reinterpret_cast<const int4*>(S + (long)(sn + rS)      * DD + cS);
            s1_ = *reinterpret_cast<const int4*>(S + (long)(sn + rS + 16) * DD + cS);
            s2_ = *reinterpret_cast<const int4*>(S + (long)(sn + rS + 32) * DD + cS);
            s3_ = *reinterpret_cast<const int4*>(S + (long)(sn + rS + 48) * DD + cS);
        }
        {
            long wb = wbase0 + s * 64;
            aw00_ = *reinterpret_cast<const half8*>(W + wb);
            aw01_ = *reinterpret_cast<const half8*>(W + wb + 16L * sW);
            aw10_ = *reinterpret_cast<const half8*>(W + wb + 32);
            aw11_ = *reinterpret_cast<const half8*>(W + wb + 16L * sW + 32);
        }

        // GEMM1 (swapped): a1[fn][fm] = mfma(S_frag, R_frag)
        f32x4 a1[2][FMA];
#pragma unroll
        for (int i = 0; i < 2; i++)
#pragma unroll
            for (int j = 0; j < FMA; j++) a1[i][j] = (f32x4)(0.0f);
#pragma unroll
        for (int kk = 0; kk < 4; kk++) {
            int klane = kk * 32 + 8 * (lane >> 4);
            half8 bf[2];
#pragma unroll
            for (int fn = 0; fn < 2; fn++)
                bf[fn] = *reinterpret_cast<const half8*>(&Ss[(wn * 32 + fn * 16 + (lane & 15)) * 136 + klane]);
#pragma unroll
            for (int fn = 0; fn < 2; fn++)
#pragma unroll
                for (int fm = 0; fm < FMA; fm++)
                    a1[fn][fm] = __builtin_amdgcn_mfma_f32_16x16x32_f16(bf[fn], af[fm][kk], a1[fn][fm], 0, 0, 0);
        }
        // tanh -> Cts [res][strm]
#pragma unroll
        for (int fn = 0; fn < 2; fn++)
#pragma unroll
            for (int fm = 0; fm < FMA; fm++) {
                int res   = wm * HRES + fm * 16 + (lane & 15);
                int strm0 = wn * 32 + fn * 16 + 4 * (lane >> 4);
                half4 hv;
                hv.x = (_Float16)ftanh(a1[fn][fm][0]);
                hv.y = (_Float16)ftanh(a1[fn][fm][1]);
                hv.z = (_Float16)ftanh(a1[fn][fm][2]);
                hv.w = (_Float16)ftanh(a1[fn][fm][3]);
                *reinterpret_cast<half4*>(&Cts[res * 72 + strm0]) = hv;
            }
        __syncthreads();                  // (B) Cts visible; Ss free

        // GEMM2: acc2[k, res] += sum_strm W[k,strm]*Cts[res,strm]
        {
            int klane = 8 * (lane >> 4);
            half8 bf2[FMA];
#pragma unroll
            for (int fn2 = 0; fn2 < FMA; fn2++)
                bf2[fn2] = *reinterpret_cast<const half8*>(&Cts[(wn * HRES + fn2 * 16 + (lane & 15)) * 72 + klane]);
#pragma unroll
            for (int fn2 = 0; fn2 < FMA; fn2++) {
                acc2[0][fn2] = __builtin_amdgcn_mfma_f32_16x16x32_f16(aw00_, bf2[fn2], acc2[0][fn2], 0, 0, 0);
                acc2[1][fn2] = __builtin_amdgcn_mfma_f32_16x16x32_f16(aw01_, bf2[fn2], acc2[1][fn2], 0, 0, 0);
            }
        }
        {
            int klane = 32 + 8 * (lane >> 4);
            half8 bf2[FMA];
#pragma unroll
            for (int fn2 = 0; fn2 < FMA; fn2++)
                bf2[fn2] = *reinterpret_cast<const half8*>(&Cts[(wn * HRES + fn2 * 16 + (lane & 15)) * 72 + klane]);
#pragma unroll
            for (int fn2 = 0; fn2 < FMA; fn2++) {
                acc2[0][fn2] = __builtin_amdgcn_mfma_f32_16x16x32_f16(aw10_, bf2[fn2], acc2[0][fn2], 0, 0, 0);
                acc2[1][fn2] = __builtin_amdgcn_mfma_f32_16x16x32_f16(aw11_, bf2[fn2], acc2[1][fn2], 0, 0, 0);
            }
        }

        if (s + 1 < nsteps) {
            *reinterpret_cast<int4*>(&Ss[(rS)      * 136 + cS]) = s0_;
            *reinterpret_cast<int4*>(&Ss[(rS + 16) * 136 + cS]) = s1_;
            *reinterpret_cast<int4*>(&Ss[(rS + 32) * 136 + cS]) = s2_;
            *reinterpret_cast<int4*>(&Ss[(rS + 48) * 136 + cS]) = s3_;
        }
    }

    // epilogue: + Add, tanh, dot w, block reduce over k. sred overlays Ss (dead now).
    float* sred = reinterpret_cast<float*>(Ss);
    float ps[FMA];
#pragma unroll
    for (int j = 0; j < FMA; j++) ps[j] = 0.f;
#pragma unroll
    for (int fm2 = 0; fm2 < 2; fm2++)
#pragma unroll
        for (int fn2 = 0; fn2 < FMA; fn2++)
#pragma unroll
            for (int r = 0; r < 4; r++) {
                int k   = wm * 32 + fm2 * 16 + (lane >> 4) * 4 + r;
                int col = wn * HRES + fn2 * 16 + (lane & 15);
                float v = ftanh(acc2[fm2][fn2][r] + (float)Add[(long)k * Ntot + n0 + col]);
                ps[fn2] += wsh[k] * v;
            }
#pragma unroll
    for (int fn2 = 0; fn2 < FMA; fn2++)
        sred[(wm * 4 + (lane >> 4)) * RES + wn * HRES + fn2 * 16 + (lane & 15)] = ps[fn2];
    __syncthreads();
    if (tid < RES) {
        float sacc = 0.f;
#pragma unroll
        for (int j = 0; j < 8; j++) sacc += sred[j * RES + tid];
        out[n0 + tid] = sacc;
    }
}

// ---------------- fused C + H + score kernel: 1024 equal-duration blocks, 4/CU ----------
// [0,512): side C, RES=64, nsteps=16 ; [512,1024): side P, RES=128, nsteps=8.
// Equal work/block -> no per-CU tail. XCD swizzle (T1) on both sides.
__global__ __launch_bounds__(256, 4)
void k_score_fused(const _Float16* __restrict__ drug_h, const _Float16* __restrict__ tb_h,
                   const _Float16* __restrict__ Wxd_h, const _Float16* __restrict__ Wpt_h,
                   const float* __restrict__ whx, const float* __restrict__ whp,
                   float* __restrict__ sc_c, float* __restrict__ sc_p)
{
    __shared__ alignas(16) _Float16 Ss[64 * 136];   // streamed [64][128+8]; epilogue: sred overlay
    __shared__ alignas(16) _Float16 Cts[128 * 72];  // C tile [RES][64+8] (side C uses half)
    __shared__ float wsh[64];

    int P = blockIdx.x;
    int tid = threadIdx.x;

    if (P < 512) {                         // side C: 64 batches x 8 l-tiles of 64
        int x = P & 7, j = P >> 3;         // j in [0,64)
        int b = x * 8 + (j >> 3);
        int n0 = (j & 7) * 64;
        score_side<2>(drug_h + (long)b * (LD * DD), tb_h + (long)b * (LP * DD),
                      Wpt_h + (long)b * (KK * LP), Wxd_h + (long)b * (KK * LD),
                      whx, sc_c + (long)b * LD, n0, LP / 64, LD, LP, Ss, Cts, wsh, tid);
    } else {                               // side P: 64 batches x 8 p-tiles of 128
        int Q = P - 512;
        int x = Q & 7, j = Q >> 3;         // j in [0,64)
        int b = x * 8 + (j >> 3);
        int n0 = (j & 7) * 128;
        score_side<4>(tb_h + (long)b * (LP * DD), drug_h + (long)b * (LD * DD),
                      Wxd_h + (long)b * (KK * LD), Wpt_h + (long)b * (KK * LP),
                      whp, sc_p + (long)b * LP, n0, LD / 64, LP, LD, Ss, Cts, wsh, tid);
    }
}

// ---------------- softmax over scores ----------------
__device__ __forceinline__ float wred_max(float v) {
#pragma unroll
    for (int off = 32; off > 0; off >>= 1) v = fmaxf(v, __shfl_xor(v, off, 64));
    return v;
}
__device__ __forceinline__ float wred_sum(float v) {
#pragma unroll
    for (int off = 32; off > 0; off >>= 1) v += __shfl_xor(v, off, 64);
    return v;
}

__global__ __launch_bounds__(1024)
void k_soft(const float* __restrict__ scc, const float* __restrict__ scp,
            float* __restrict__ ac, float* __restrict__ ap)
{
    __shared__ float r16[16];
    int b = blockIdx.x, tid = threadIdx.x;
    int lane = tid & 63, wid = tid >> 6;

    float s = (tid < 512) ? scc[b * 512 + tid] : -3.4e38f;
    float m = wred_max(s);
    if (lane == 0) r16[wid] = m;
    __syncthreads();
    m = r16[0];
#pragma unroll
    for (int i = 1; i < 16; i++) m = fmaxf(m, r16[i]);
    float e = (tid < 512) ? __expf(s - m) : 0.f;
    __syncthreads();
    float t = wred_sum(e);
    if (lane == 0) r16[wid] = t;
    __syncthreads();
    float sum = 0.f;
#pragma unroll
    for (int i = 0; i < 16; i++) sum += r16[i];
    if (tid < 512) ac[b * 512 + tid] = e * __builtin_amdgcn_rcpf(sum);
    __syncthreads();

    float s2 = scp[b * 1024 + tid];
    float m2 = wred_max(s2);
    if (lane == 0) r16[wid] = m2;
    __syncthreads();
    m2 = r16[0];
#pragma unroll
    for (int i = 1; i < 16; i++) m2 = fmaxf(m2, r16[i]);
    float e2 = __expf(s2 - m2);
    __syncthreads();
    float t2 = wred_sum(e2);
    if (lane == 0) r16[wid] = t2;
    __syncthreads();
    float sum2 = 0.f;
#pragma unroll
    for (int i = 0; i < 16; i++) sum2 += r16[i];
    ap[b * 1024 + tid] = e2 * __builtin_amdgcn_rcpf(sum2);
}

// ---------------- weighted sums: out[b,d] = sum_l a[l] * X[b,l,d] ----------------
__global__ __launch_bounds__(512)
void k_wsum(const _Float16* __restrict__ drug_h, const _Float16* __restrict__ targ_h,
            const float* __restrict__ ac, const float* __restrict__ ap,
            float* __restrict__ out)
{
    __shared__ float ash[1024];
    __shared__ float red[32 * 128];
    int b = blockIdx.x, side = blockIdx.y;
    int L = side ? LP : LD;
    const _Float16* X = side ? targ_h : drug_h;
    const float* a = side ? ap : ac;
    float* ob = out + side * 8192 + b * 128;
    int tid = threadIdx.x;

    for (int i = tid; i < L; i += 512) ash[i] = a[(long)b * L + i];
    __syncthreads();

    int col8 = tid & 15, rg = tid >> 4;
    float accv[8];
#pragma unroll
    for (int j = 0; j < 8; j++) accv[j] = 0.f;
    const _Float16* Xb = X + (long)b * L * 128;
    for (int l = rg; l < L; l += 32) {
        half8 v = *reinterpret_cast<const half8*>(&Xb[l * 128 + col8 * 8]);
        float av = ash[l];
#pragma unroll
        for (int j = 0; j < 8; j++) accv[j] += av * (float)v[j];
    }
#pragma unroll
    for (int j = 0; j < 8; j++) red[rg * 128 + col8 * 8 + j] = accv[j];
    __syncthreads();
    if (tid < 128) {
        float s = 0.f;
#pragma unroll
        for (int g = 0; g < 32; g++) s += red[g * 128 + tid];
        ob[tid] = s;
    }
}

// ---------------- launch ----------------
extern "C" void kernel_launch(void* const* d_in, const int* in_sizes, int n_in,
                              void* d_out, int out_size, void* d_ws, size_t ws_size,
                              hipStream_t stream) {
    (void)in_sizes; (void)n_in; (void)out_size;
    const float* drug   = (const float*)d_in[0];
    const float* target = (const float*)d_in[1];
    const float* Wb     = (const float*)d_in[2];
    const float* Wx     = (const float*)d_in[3];
    const float* Wp     = (const float*)d_in[4];
    const float* whx    = (const float*)d_in[5];
    const float* whp    = (const float*)d_in[6];

    char* w = (char*)d_ws;
    size_t off = 0;
    auto takeb = [&](size_t bytes) {
        void* p = (void*)(w + off);
        off += (bytes + 255) & ~(size_t)255;
        return p;
    };
    _Float16* drug_h = (_Float16*)takeb((size_t)NB * LD * DD * 2);
    _Float16* targ_h = (_Float16*)takeb((size_t)NB * LP * DD * 2);
    _Float16* WbT_h  = (_Float16*)takeb(128 * 128 * 2);
    _Float16* Wx_h   = (_Float16*)takeb(64 * 128 * 2);
    _Float16* Wp_h   = (_Float16*)takeb(64 * 128 * 2);
    _Float16* tb_h   = (_Float16*)takeb((size_t)NB * LP * DD * 2);
    _Float16* Wxd_h  = (_Float16*)takeb((size_t)NB * KK * LD * 2);
    _Float16* Wpt_h  = (_Float16*)takeb((size_t)NB * KK * LP * 2);
    float*    sc_c   = (float*)takeb((size_t)NB * LD * 4);
    float*    sc_p   = (float*)takeb((size_t)NB * LP * 4);
    float*    a_c    = (float*)takeb((size_t)NB * LD * 4);
    float*    a_p    = (float*)takeb((size_t)NB * LP * 4);

    if (off > ws_size) {                 // workspace shortfall -> sentinel (absmax ~1000)
        k_sentinel<<<1, 64, 0, stream>>>((float*)d_out);
        return;
    }

    k_convprep<<<2128, 256, 0, stream>>>(drug, drug_h, target, targ_h,
                                         Wb, WbT_h, Wx, Wx_h, Wp, Wp_h);

    // merged: Wxd + Wpt + tb in one dispatch
    k_gemm3<<<dim3(1792), 256, 0, stream>>>(
        drug_h, targ_h, WbT_h, Wx_h, Wp_h, tb_h, Wxd_h, Wpt_h);

    // fused: C recomputed per side in-LDS; scores out directly (1024 equal blocks, 4/CU)
    k_score_fused<<<dim3(1024), 256, 0, stream>>>(
        drug_h, tb_h, Wxd_h, Wpt_h, whx, whp, sc_c, sc_p);

    k_soft<<<NB, 1024, 0, stream>>>(sc_c, sc_p, a_c, a_p);
    k_wsum<<<dim3(NB, 2), 512, 0, stream>>>(drug_h, targ_h, a_c, a_p, (float*)d_out);
}

// Round 23
// 82.337 us; speedup vs baseline: 1.2726x; 1.2726x over previous
//
#include <hip/hip_runtime.h>
#include <hip/hip_bf16.h>
#include <math.h>

#define NB 64
#define LD 512
#define LP 1024
#define DD 128
#define KK 64

using half8 = __attribute__((ext_vector_type(8))) _Float16;
using half4 = __attribute__((ext_vector_type(4))) _Float16;
using f32x4 = __attribute__((ext_vector_type(4))) float;

// fast tanh: 1 - 2*rcp(e^{2x}+1) via v_rcp_f32 (no IEEE div sequence).
__device__ __forceinline__ float ftanh(float x) {
    float e = __expf(2.0f * x);
    return 1.0f - 2.0f * __builtin_amdgcn_rcpf(e + 1.0f);
}

__global__ void k_sentinel(float* out) {
    if (threadIdx.x == 0 && blockIdx.x == 0) out[0] = 1000.0f;
}

// ---------------- merged front-end: drug conv + targ conv + WbT + Wx/Wp ----------------
__global__ void k_convprep(const float* __restrict__ drug, _Float16* __restrict__ drug_h,
                           const float* __restrict__ targ, _Float16* __restrict__ targ_h,
                           const float* __restrict__ Wb, _Float16* __restrict__ WbT,
                           const float* __restrict__ Wx, _Float16* __restrict__ Wx_h,
                           const float* __restrict__ Wp, _Float16* __restrict__ Wp_h)
{
    int bid = blockIdx.x, tid = threadIdx.x;
    if (bid < 2048) {
        const float* in = (bid < 1024) ? drug : targ;
        _Float16* out = (bid < 1024) ? drug_h : targ_h;
        int n = (bid < 1024) ? (NB * LD * DD) : (NB * LP * DD);
        int blk = bid & 1023;
        int i = (blk * 256 + tid) * 4;
        int stride = 1024 * 256 * 4;
        for (; i < n; i += stride) {
            float4 v = *reinterpret_cast<const float4*>(in + i);
            half4 h;
            h.x = (_Float16)v.x; h.y = (_Float16)v.y; h.z = (_Float16)v.z; h.w = (_Float16)v.w;
            *reinterpret_cast<half4*>(out + i) = h;
        }
    } else if (bid < 2112) {
        int t = (bid - 2048) * 256 + tid;
        int d = t >> 7, e = t & 127;
        WbT[t] = (_Float16)Wb[e * 128 + d];
    } else {
        int q = bid - 2112;
        const float* src = (q < 8) ? Wx : Wp;
        _Float16* dst = (q < 8) ? Wx_h : Wp_h;
        int i = ((q & 7) * 256 + tid) * 4;
        float4 v = *reinterpret_cast<const float4*>(src + i);
        half4 h;
        h.x = (_Float16)v.x; h.y = (_Float16)v.y; h.z = (_Float16)v.z; h.w = (_Float16)v.w;
        *reinterpret_cast<half4*>(dst + i) = h;
    }
}

// ---------------- merged NT GEMM dispatch: Wxd + Wpt + tb in one grid ----------------
__global__ __launch_bounds__(256)
void k_gemm3(const _Float16* __restrict__ drug_h, const _Float16* __restrict__ targ_h,
             const _Float16* __restrict__ WbT_h, const _Float16* __restrict__ Wx_h,
             const _Float16* __restrict__ Wp_h,
             _Float16* __restrict__ tb_h, _Float16* __restrict__ Wxd_h,
             _Float16* __restrict__ Wpt_h)
{
    __shared__ alignas(16) _Float16 smem[64 * 72 + 128 * 72];
    _Float16* As = smem;
    _Float16* Bs = smem + 64 * 72;

    int bid = blockIdx.x;
    const _Float16 *A, *Bm;
    _Float16* Out;
    long sA, sB, sOut;
    int N, tilesN, t;
    const int Kd = 128;
    if (bid < 256)      { A = Wx_h;  sA = 0;            Bm = drug_h; sB = (long)LD * DD; Out = Wxd_h; sOut = (long)KK * LD; N = LD;  tilesN = 4; t = bid; }
    else if (bid < 768) { A = Wp_h;  sA = 0;            Bm = targ_h; sB = (long)LP * DD; Out = Wpt_h; sOut = (long)KK * LP; N = LP;  tilesN = 8; t = bid - 256; }
    else                { A = targ_h; sA = (long)LP * DD; Bm = WbT_h; sB = 0;            Out = tb_h;  sOut = (long)LP * DD; N = 128; tilesN = 1; t = bid - 768; }

    int tpb = (tilesN == 1) ? 16 : tilesN;
    int b = t / tpb;
    int q = t % tpb;
    int m0 = (tilesN == 1) ? q * 64 : 0;
    int n0 = (tilesN == 1) ? 0 : q * 128;

    const _Float16* Ab = A + (long)b * sA;
    const _Float16* Bb = Bm + (long)b * sB;

    int tid = threadIdx.x;
    int lane = tid & 63;
    int wid = tid >> 6;
    int wm = wid & 1, wn = wid >> 1;

    f32x4 acc[2][4];
#pragma unroll
    for (int i = 0; i < 2; i++)
#pragma unroll
        for (int j = 0; j < 4; j++) acc[i][j] = (f32x4)(0.0f);

    for (int k0 = 0; k0 < Kd; k0 += 64) {
#pragma unroll
        for (int i = 0; i < 2; i++) {
            int c = tid + i * 256;
            int row = c >> 3, col = c & 7;
            int4 v = *reinterpret_cast<const int4*>(Ab + (long)(m0 + row) * Kd + k0 + col * 8);
            *reinterpret_cast<int4*>(&As[row * 72 + col * 8]) = v;
        }
#pragma unroll
        for (int i = 0; i < 4; i++) {
            int c = tid + i * 256;
            int row = c >> 3, col = c & 7;
            int4 v = *reinterpret_cast<const int4*>(Bb + (long)(n0 + row) * Kd + k0 + col * 8);
            *reinterpret_cast<int4*>(&Bs[row * 72 + col * 8]) = v;
        }
        __syncthreads();
#pragma unroll
        for (int kk = 0; kk < 64; kk += 32) {
            int klane = kk + 8 * (lane >> 4);
            half8 af[2], bfr[4];
#pragma unroll
            for (int fm = 0; fm < 2; fm++)
                af[fm] = *reinterpret_cast<const half8*>(&As[(wm * 32 + fm * 16 + (lane & 15)) * 72 + klane]);
#pragma unroll
            for (int fn = 0; fn < 4; fn++)
                bfr[fn] = *reinterpret_cast<const half8*>(&Bs[(wn * 64 + fn * 16 + (lane & 15)) * 72 + klane]);
#pragma unroll
            for (int fm = 0; fm < 2; fm++)
#pragma unroll
                for (int fn = 0; fn < 4; fn++)
                    acc[fm][fn] = __builtin_amdgcn_mfma_f32_16x16x32_f16(af[fm], bfr[fn], acc[fm][fn], 0, 0, 0);
        }
        __syncthreads();
    }

    long ob = (long)b * sOut;
#pragma unroll
    for (int fm = 0; fm < 2; fm++)
#pragma unroll
        for (int fn = 0; fn < 4; fn++)
#pragma unroll
            for (int r = 0; r < 4; r++) {
                int row = m0 + wm * 32 + fm * 16 + (lane >> 4) * 4 + r;
                int col = n0 + wn * 64 + fn * 16 + (lane & 15);
                Out[ob + (long)row * N + col] = (_Float16)acc[fm][fn][r];
            }
}

// ---------------- fused C + H + score kernel, RES=128, 2-barrier pipeline (R21) ---------
// side C (P < 256):  res = drug l (128 rows), stream = tb p; nsteps=16
// side P (P >= 256): res = tb p (128 rows), stream = drug l; nsteps=8
// 768 blocks = exactly 3/CU (LDS ~40 KB). XCD swizzle (T1). W operands via regs.
__global__ __launch_bounds__(256, 3)
void k_score_fused(const _Float16* __restrict__ drug_h, const _Float16* __restrict__ tb_h,
                   const _Float16* __restrict__ Wxd_h, const _Float16* __restrict__ Wpt_h,
                   const float* __restrict__ whx, const float* __restrict__ whp,
                   float* __restrict__ sc_c, float* __restrict__ sc_p)
{
    __shared__ alignas(16) _Float16 Ss[64 * 136];   // streamed [64][128+8]
    __shared__ alignas(16) _Float16 Cts[128 * 72];  // C tile   [128res][64strm+8]
    __shared__ float sred[8 * 128];
    __shared__ float wsh[64];

    int P = blockIdx.x;
    int tid = threadIdx.x;
    int lane = tid & 63;
    int wid = tid >> 6;
    int wm = wid & 1, wn = wid >> 1;

    int b, n0, nsteps, Ntot, sW;
    const _Float16 *R, *S, *W, *Add;
    const float* wv;
    float* out;
    if (P < 256) {
        int x = P & 7, j = P >> 3;            // j in [0,32)
        b = x * 8 + (j >> 2);                  // batches [8x,8x+8) on XCD x
        n0 = (j & 3) * 128;
        R = drug_h + (long)b * (LD * DD);
        S = tb_h   + (long)b * (LP * DD);
        W = Wpt_h  + (long)b * (KK * LP);  sW = LP;
        Add = Wxd_h + (long)b * (KK * LD); Ntot = LD;
        nsteps = LP / 64; wv = whx; out = sc_c + (long)b * LD;
    } else {
        int Q = P - 256;
        int x = Q & 7, j = Q >> 3;            // j in [0,64)
        b = x * 8 + (j >> 3);
        n0 = (j & 7) * 128;
        R = tb_h   + (long)b * (LP * DD);
        S = drug_h + (long)b * (LD * DD);
        W = Wxd_h  + (long)b * (KK * LD);  sW = LD;
        Add = Wpt_h + (long)b * (KK * LP); Ntot = LP;
        nsteps = LD / 64; wv = whp; out = sc_p + (long)b * LP;
    }

    // resident fragments in registers (MFMA B-operand): 128 rows = wm*64 + fm*16 + (lane&15)
    half8 af[4][4];
#pragma unroll
    for (int fm = 0; fm < 4; fm++)
#pragma unroll
        for (int kk = 0; kk < 4; kk++) {
            int row = n0 + wm * 64 + fm * 16 + (lane & 15);
            int col = kk * 32 + 8 * (lane >> 4);
            af[fm][kk] = *reinterpret_cast<const half8*>(R + (long)row * DD + col);
        }
    if (tid < 64) wsh[tid] = wv[tid];

    // streamed-tile register pipeline (named scalars; affine addresses)
    int rS = tid >> 4, cS = (tid & 15) * 8;     // S rows rS, rS+16, rS+32, rS+48
    int4 s0_, s1_, s2_, s3_;
    s0_ = *reinterpret_cast<const int4*>(S + (long)(rS)      * DD + cS);
    s1_ = *reinterpret_cast<const int4*>(S + (long)(rS + 16) * DD + cS);
    s2_ = *reinterpret_cast<const int4*>(S + (long)(rS + 32) * DD + cS);
    s3_ = *reinterpret_cast<const int4*>(S + (long)(rS + 48) * DD + cS);
    *reinterpret_cast<int4*>(&Ss[(rS)      * 136 + cS]) = s0_;
    *reinterpret_cast<int4*>(&Ss[(rS + 16) * 136 + cS]) = s1_;
    *reinterpret_cast<int4*>(&Ss[(rS + 32) * 136 + cS]) = s2_;
    *reinterpret_cast<int4*>(&Ss[(rS + 48) * 136 + cS]) = s3_;

    // W fragment regs (GEMM2 A-operand), loaded fresh each step, one phase ahead of use
    half8 aw00_, aw01_, aw10_, aw11_;
    long wbase0 = (long)(wm * 32 + (lane & 15)) * sW + 8 * (lane >> 4);

    f32x4 acc2[2][4];
#pragma unroll
    for (int i = 0; i < 2; i++)
#pragma unroll
        for (int j = 0; j < 4; j++) acc2[i][j] = (f32x4)(0.0f);

    for (int s = 0; s < nsteps; s++) {
        __syncthreads();                  // (C) Ss(s) visible; Cts free (prev GEMM2 done)
        if (s + 1 < nsteps) {
            int sn = (s + 1) * 64;
            s0_ = *reinterpret_cast<const int4*>(S + (long)(sn + rS)      * DD + cS);
            s1_ = *reinterpret_cast<const int4*>(S + (long)(sn + rS + 16) * DD + cS);
            s2_ = *reinterpret_cast<const int4*>(S + (long)(sn + rS + 32) * DD + cS);
            s3_ = *reinterpret_cast<const int4*>(S + (long)(sn + rS + 48) * DD + cS);
        }
        {
            long wb = wbase0 + s * 64;
            aw00_ = *reinterpret_cast<const half8*>(W + wb);
            aw01_ = *reinterpret_cast<const half8*>(W + wb + 16L * sW);
            aw10_ = *reinterpret_cast<const half8*>(W + wb + 32);
            aw11_ = *reinterpret_cast<const half8*>(W + wb + 16L * sW + 32);
        }

        // GEMM1 (swapped): a1[fn][fm] = mfma(S_frag, R_frag)
        f32x4 a1[2][4];
#pragma unroll
        for (int i = 0; i < 2; i++)
#pragma unroll
            for (int j = 0; j < 4; j++) a1[i][j] = (f32x4)(0.0f);
#pragma unroll
        for (int kk = 0; kk < 4; kk++) {
            int klane = kk * 32 + 8 * (lane >> 4);
            half8 bf[2];
#pragma unroll
            for (int fn = 0; fn < 2; fn++)
                bf[fn] = *reinterpret_cast<const half8*>(&Ss[(wn * 32 + fn * 16 + (lane & 15)) * 136 + klane]);
#pragma unroll
            for (int fn = 0; fn < 2; fn++)
#pragma unroll
                for (int fm = 0; fm < 4; fm++)
                    a1[fn][fm] = __builtin_amdgcn_mfma_f32_16x16x32_f16(bf[fn], af[fm][kk], a1[fn][fm], 0, 0, 0);
        }
        // tanh -> Cts [res][strm]
#pragma unroll
        for (int fn = 0; fn < 2; fn++)
#pragma unroll
            for (int fm = 0; fm < 4; fm++) {
                int res   = wm * 64 + fm * 16 + (lane & 15);
                int strm0 = wn * 32 + fn * 16 + 4 * (lane >> 4);
                half4 hv;
                hv.x = (_Float16)ftanh(a1[fn][fm][0]);
                hv.y = (_Float16)ftanh(a1[fn][fm][1]);
                hv.z = (_Float16)ftanh(a1[fn][fm][2]);
                hv.w = (_Float16)ftanh(a1[fn][fm][3]);
                *reinterpret_cast<half4*>(&Cts[res * 72 + strm0]) = hv;
            }
        __syncthreads();                  // (B) Cts visible; GEMM1 done -> Ss free

        // GEMM2: acc2[k, res] += sum_strm W[k,strm]*Cts[res,strm]  (aw in regs)
        {
            int klane = 8 * (lane >> 4);          // kk = 0
            half8 bf2[4];
#pragma unroll
            for (int fn2 = 0; fn2 < 4; fn2++)
                bf2[fn2] = *reinterpret_cast<const half8*>(&Cts[(wn * 64 + fn2 * 16 + (lane & 15)) * 72 + klane]);
#pragma unroll
            for (int fn2 = 0; fn2 < 4; fn2++) {
                acc2[0][fn2] = __builtin_amdgcn_mfma_f32_16x16x32_f16(aw00_, bf2[fn2], acc2[0][fn2], 0, 0, 0);
                acc2[1][fn2] = __builtin_amdgcn_mfma_f32_16x16x32_f16(aw01_, bf2[fn2], acc2[1][fn2], 0, 0, 0);
            }
        }
        {
            int klane = 32 + 8 * (lane >> 4);     // kk = 1
            half8 bf2[4];
#pragma unroll
            for (int fn2 = 0; fn2 < 4; fn2++)
                bf2[fn2] = *reinterpret_cast<const half8*>(&Cts[(wn * 64 + fn2 * 16 + (lane & 15)) * 72 + klane]);
#pragma unroll
            for (int fn2 = 0; fn2 < 4; fn2++) {
                acc2[0][fn2] = __builtin_amdgcn_mfma_f32_16x16x32_f16(aw10_, bf2[fn2], acc2[0][fn2], 0, 0, 0);
                acc2[1][fn2] = __builtin_amdgcn_mfma_f32_16x16x32_f16(aw11_, bf2[fn2], acc2[1][fn2], 0, 0, 0);
            }
        }

        // tail: write next S tile to LDS (overlaps GEMM2 completion; visible at next C)
        if (s + 1 < nsteps) {
            *reinterpret_cast<int4*>(&Ss[(rS)      * 136 + cS]) = s0_;
            *reinterpret_cast<int4*>(&Ss[(rS + 16) * 136 + cS]) = s1_;
            *reinterpret_cast<int4*>(&Ss[(rS + 32) * 136 + cS]) = s2_;
            *reinterpret_cast<int4*>(&Ss[(rS + 48) * 136 + cS]) = s3_;
        }
    }

    // epilogue: + Add, tanh, dot w, block reduce over k
    float ps[4] = {0.f, 0.f, 0.f, 0.f};
#pragma unroll
    for (int fm2 = 0; fm2 < 2; fm2++)
#pragma unroll
        for (int fn2 = 0; fn2 < 4; fn2++)
#pragma unroll
            for (int r = 0; r < 4; r++) {
                int k   = wm * 32 + fm2 * 16 + (lane >> 4) * 4 + r;
                int col = wn * 64 + fn2 * 16 + (lane & 15);
                float v = ftanh(acc2[fm2][fn2][r] + (float)Add[(long)k * Ntot + n0 + col]);
                ps[fn2] += wsh[k] * v;
            }
#pragma unroll
    for (int fn2 = 0; fn2 < 4; fn2++)
        sred[(wm * 4 + (lane >> 4)) * 128 + wn * 64 + fn2 * 16 + (lane & 15)] = ps[fn2];
    __syncthreads();
    if (tid < 128) {
        float sacc = 0.f;
#pragma unroll
        for (int j = 0; j < 8; j++) sacc += sred[j * 128 + tid];
        out[n0 + tid] = sacc;
    }
}

// ---------------- merged softmax + weighted sum ----------------
__device__ __forceinline__ float wred_max(float v) {
#pragma unroll
    for (int off = 32; off > 0; off >>= 1) v = fmaxf(v, __shfl_xor(v, off, 64));
    return v;
}
__device__ __forceinline__ float wred_sum(float v) {
#pragma unroll
    for (int off = 32; off > 0; off >>= 1) v += __shfl_xor(v, off, 64);
    return v;
}

// out[b, side*128 + d] = sum_l softmax(sc)[l] * X[b,l,d]
__global__ __launch_bounds__(512)
void k_wsoft(const _Float16* __restrict__ drug_h, const _Float16* __restrict__ targ_h,
             const float* __restrict__ scc, const float* __restrict__ scp,
             float* __restrict__ out)
{
    __shared__ float ash[1024];
    __shared__ float red[32 * 128];
    __shared__ float r8a[8];
    __shared__ float r8b[8];
    int b = blockIdx.x, side = blockIdx.y;
    int L = side ? LP : LD;
    const _Float16* X = side ? targ_h : drug_h;
    const float* sc = side ? (scp + (long)b * LP) : (scc + (long)b * LD);
    float* ob = out + side * 8192 + b * 128;
    int tid = threadIdx.x, lane = tid & 63, wid = tid >> 6;

    // softmax over L scores (512 threads; side P handles 2 elems/thread)
    float s0 = sc[tid];
    float s1 = side ? sc[tid + 512] : -3.4e38f;
    float m = wred_max(fmaxf(s0, s1));
    if (lane == 0) r8a[wid] = m;
    __syncthreads();
    m = r8a[0];
#pragma unroll
    for (int i = 1; i < 8; i++) m = fmaxf(m, r8a[i]);
    float e0 = __expf(s0 - m);
    float e1 = side ? __expf(s1 - m) : 0.f;
    float t = wred_sum(e0 + e1);
    if (lane == 0) r8b[wid] = t;
    __syncthreads();
    float sum = 0.f;
#pragma unroll
    for (int i = 0; i < 8; i++) sum += r8b[i];
    float rs = __builtin_amdgcn_rcpf(sum);
    ash[tid] = e0 * rs;
    if (side) ash[tid + 512] = e1 * rs;
    __syncthreads();

    // weighted sum over L rows of X (fp16, coalesced half8)
    int col8 = tid & 15, rg = tid >> 4;
    float accv[8];
#pragma unroll
    for (int j = 0; j < 8; j++) accv[j] = 0.f;
    const _Float16* Xb = X + (long)b * L * 128;
    for (int l = rg; l < L; l += 32) {
        half8 v = *reinterpret_cast<const half8*>(&Xb[l * 128 + col8 * 8]);
        float av = ash[l];
#pragma unroll
        for (int j = 0; j < 8; j++) accv[j] += av * (float)v[j];
    }
#pragma unroll
    for (int j = 0; j < 8; j++) red[rg * 128 + col8 * 8 + j] = accv[j];
    __syncthreads();
    if (tid < 128) {
        float s = 0.f;
#pragma unroll
        for (int g = 0; g < 32; g++) s += red[g * 128 + tid];
        ob[tid] = s;
    }
}

// ---------------- launch ----------------
extern "C" void kernel_launch(void* const* d_in, const int* in_sizes, int n_in,
                              void* d_out, int out_size, void* d_ws, size_t ws_size,
                              hipStream_t stream) {
    (void)in_sizes; (void)n_in; (void)out_size;
    const float* drug   = (const float*)d_in[0];
    const float* target = (const float*)d_in[1];
    const float* Wb     = (const float*)d_in[2];
    const float* Wx     = (const float*)d_in[3];
    const float* Wp     = (const float*)d_in[4];
    const float* whx    = (const float*)d_in[5];
    const float* whp    = (const float*)d_in[6];

    char* w = (char*)d_ws;
    size_t off = 0;
    auto takeb = [&](size_t bytes) {
        void* p = (void*)(w + off);
        off += (bytes + 255) & ~(size_t)255;
        return p;
    };
    _Float16* drug_h = (_Float16*)takeb((size_t)NB * LD * DD * 2);
    _Float16* targ_h = (_Float16*)takeb((size_t)NB * LP * DD * 2);
    _Float16* WbT_h  = (_Float16*)takeb(128 * 128 * 2);
    _Float16* Wx_h   = (_Float16*)takeb(64 * 128 * 2);
    _Float16* Wp_h   = (_Float16*)takeb(64 * 128 * 2);
    _Float16* tb_h   = (_Float16*)takeb((size_t)NB * LP * DD * 2);
    _Float16* Wxd_h  = (_Float16*)takeb((size_t)NB * KK * LD * 2);
    _Float16* Wpt_h  = (_Float16*)takeb((size_t)NB * KK * LP * 2);
    float*    sc_c   = (float*)takeb((size_t)NB * LD * 4);
    float*    sc_p   = (float*)takeb((size_t)NB * LP * 4);

    if (off > ws_size) {                 // workspace shortfall -> sentinel (absmax ~1000)
        k_sentinel<<<1, 64, 0, stream>>>((float*)d_out);
        return;
    }

    k_convprep<<<2128, 256, 0, stream>>>(drug, drug_h, target, targ_h,
                                         Wb, WbT_h, Wx, Wx_h, Wp, Wp_h);

    // merged: Wxd + Wpt + tb in one dispatch
    k_gemm3<<<dim3(1792), 256, 0, stream>>>(
        drug_h, targ_h, WbT_h, Wx_h, Wp_h, tb_h, Wxd_h, Wpt_h);

    // fused: C recomputed per side in-LDS; scores out directly (RES=128, 768 blocks)
    k_score_fused<<<dim3(256 + 512), 256, 0, stream>>>(
        drug_h, tb_h, Wxd_h, Wpt_h, whx, whp, sc_c, sc_p);

    // merged softmax + weighted sums
    k_wsoft<<<dim3(NB, 2), 512, 0, stream>>>(drug_h, targ_h, sc_c, sc_p, (float*)d_out);
}